// Round 1
// baseline (10382.915 us; speedup 1.0000x reference)
//
#include <hip/hip_runtime.h>

#define TT 512
#define BB 256
#define HH 512
#define DD 105
#define RS 85
#define NRULE 20
#define NOUT 33

#define NFRAG_REC 512              // 32 mtiles x 16 ktiles
#define NFRAG_IN  128              // 32 mtiles x 4 ktiles (k padded 105->128)
#define NFRAG_OUT 48               // 3 mtiles (o padded 33->48) x 16 ktiles
#define FRAG_IN_OFF  (NFRAG_REC)
#define FRAG_OUT_OFF (NFRAG_REC + NFRAG_IN)
#define NFRAG_TOT (NFRAG_REC + NFRAG_IN + NFRAG_OUT)

typedef __bf16 bf16x8 __attribute__((ext_vector_type(8)));
typedef float  f32x4  __attribute__((ext_vector_type(4)));

__device__ __forceinline__ unsigned short f2bf(float f) {
  unsigned u = __builtin_bit_cast(unsigned, f);
  u += 0x7FFFu + ((u >> 16) & 1u);            // RNE
  return (unsigned short)(u >> 16);
}

// Pack Wrec*mask, [Ws|Wr] (k padded to 128 with zeros), Wout (m padded to 48
// with zeros) into MFMA 16x16x32 A-fragment layout:
// frag f = mt*KT+kt, lane l holds M[mt*16 + (l&15)][kt*32 + (l>>4)*8 + j], j=0..7
__global__ void pack_weights(const float* __restrict__ Ws_w, const float* __restrict__ Wr_w,
                             const float* __restrict__ Wrec_w, const float* __restrict__ mask,
                             const float* __restrict__ Wout_w, unsigned short* __restrict__ wp)
{
  int gid = blockIdx.x * blockDim.x + threadIdx.x;
  if (gid >= NFRAG_TOT * 64) return;
  int f = gid >> 6, lane = gid & 63;
  int m16 = lane & 15, kg = lane >> 4;
  float v[8];
  if (f < NFRAG_REC) {
    int mt = f >> 4, kt = f & 15;
    int m = mt * 16 + m16, k0 = kt * 32 + kg * 8;
#pragma unroll
    for (int j = 0; j < 8; ++j) {
      int k = k0 + j;
      v[j] = Wrec_w[m * HH + k] * mask[m * HH + k];
    }
  } else if (f < FRAG_OUT_OFF) {
    int ff = f - FRAG_IN_OFF;
    int mt = ff >> 2, kt = ff & 3;
    int m = mt * 16 + m16, k0 = kt * 32 + kg * 8;
#pragma unroll
    for (int j = 0; j < 8; ++j) {
      int k = k0 + j;
      float val = 0.f;
      if (k < RS) val = Ws_w[m * RS + k];
      else if (k < DD) val = Wr_w[m * NRULE + (k - RS)];
      v[j] = val;
    }
  } else {
    int ff = f - FRAG_OUT_OFF;
    int mt = ff >> 4, kt = ff & 15;
    int m = mt * 16 + m16, k0 = kt * 32 + kg * 8;
#pragma unroll
    for (int j = 0; j < 8; ++j) {
      int k = k0 + j;
      v[j] = (m < NOUT) ? Wout_w[m * HH + k] : 0.f;
    }
  }
  unsigned o[4];
#pragma unroll
  for (int j = 0; j < 4; ++j)
    o[j] = (unsigned)f2bf(v[2 * j]) | ((unsigned)f2bf(v[2 * j + 1]) << 16);
  uint4 st = make_uint4(o[0], o[1], o[2], o[3]);
  *reinterpret_cast<uint4*>(wp + (size_t)f * 512 + lane * 8) = st;
}

// Persistent fused RNN kernel. 16 blocks (one per 16-row batch group), 512 thr.
// Orientation: A = W (m = h_out/o), B = state (n = b). C layout: col=lane&15=b,
// row=(lane>>4)*4+r. Each lane owns 16 (h,b) state elems in f32 registers.
__global__ __launch_bounds__(512)
void rnn_fused(const float* __restrict__ x, const float* __restrict__ noise,
               const float* __restrict__ Ws_b, const float* __restrict__ Wrec_b,
               const float* __restrict__ Wout_b, const unsigned short* __restrict__ wp,
               float* __restrict__ out)
{
  __shared__ unsigned short h_lds[16 * 512];      // [b][h] bf16, XOR-swizzled
  __shared__ unsigned short x_lds[2][16 * 128];   // [b][k] bf16, swizzled, zero-padded

  const int tid  = threadIdx.x;
  const int wv   = tid >> 6;
  const int lane = tid & 63;
  const int bcol = lane & 15;
  const int krow = lane >> 4;
  const int gb   = blockIdx.x * 16;
  const int sw   = (bcol & 7) << 3;               // short-index XOR (bits 3..5)

  const uint4* wp4 = reinterpret_cast<const uint4*>(wp);

  // zero LDS (h state = 0; x pads = 0; avoid NaN poison through MFMA)
  for (int i = tid; i < 16 * 512; i += 512) h_lds[i] = 0;
  {
    unsigned short* xz = &x_lds[0][0];
    for (int i = tid; i < 2 * 16 * 128; i += 512) xz[i] = 0;
  }

  // register-resident Wrec tiles: mt = 4*wv, 4*wv+1  (128 VGPR)
  bf16x8 wreg[2][16];
#pragma unroll
  for (int j = 0; j < 2; ++j)
#pragma unroll
    for (int kt = 0; kt < 16; ++kt)
      wreg[j][kt] = __builtin_bit_cast(bf16x8, wp4[((4 * wv + j) * 16 + kt) * 64 + lane]);

  float bias_reg[4][4];
#pragma unroll
  for (int j = 0; j < 4; ++j)
#pragma unroll
    for (int r = 0; r < 4; ++r) {
      int h = (4 * wv + j) * 16 + krow * 4 + r;
      bias_reg[j][r] = Ws_b[h] + Wrec_b[h];
    }
  float woutb[4];
#pragma unroll
  for (int r = 0; r < 4; ++r) {
    int o = wv * 16 + krow * 4 + r;
    woutb[r] = (wv < 3 && o < NOUT) ? Wout_b[o] : 0.f;
  }

  float hreg[4][4] = {};      // f32 hidden state owned by this lane
  f32x4 nrA[4], nrB[4];       // prefetched noise (C-layout aligned float4s)

  __syncthreads();            // LDS zeros visible before staging

  // ---- stage t = 0 ----
  if (tid < 420) {
    f32x4 xv = reinterpret_cast<const f32x4*>(x + (size_t)gb * DD)[tid];
#pragma unroll
    for (int j = 0; j < 4; ++j) {
      int e = tid * 4 + j;
      int b = e / DD, k = e - b * DD;
      x_lds[0][b * 128 + (k ^ ((b & 7) << 3))] = f2bf(xv[j]);
    }
  }
  {
    const float* nb = noise + ((size_t)gb + bcol) * HH + krow * 4;
#pragma unroll
    for (int j = 0; j < 4; ++j)
      nrA[j] = *reinterpret_cast<const f32x4*>(nb + (4 * wv + j) * 16);
  }
  __syncthreads();

#pragma unroll 1
  for (int t = 0; t < TT; ++t) {
    const int cur = t & 1;
    // ---------------- P1 ----------------
    // prefetch t+1 tiles into registers (hidden under MFMA work)
    f32x4 xs = {0.f, 0.f, 0.f, 0.f};
    if (t + 1 < TT) {
      if (tid < 420)
        xs = reinterpret_cast<const f32x4*>(x + ((size_t)(t + 1) * BB + gb) * DD)[tid];
      const float* nb = noise + (((size_t)(t + 1)) * BB + gb + bcol) * HH + krow * 4;
#pragma unroll
      for (int j = 0; j < 4; ++j)
        nrB[j] = *reinterpret_cast<const f32x4*>(nb + (4 * wv + j) * 16);
    }

    f32x4 acc[4];
#pragma unroll
    for (int j = 0; j < 4; ++j) acc[j] = f32x4{0.f, 0.f, 0.f, 0.f};

    // recurrent GEMM: h[t-1] @ Wrec^T  (tiles 0,1 from regs; 2,3 streamed from L2)
    const int mt2 = 4 * wv + 2, mt3 = 4 * wv + 3;
#pragma unroll
    for (int kt = 0; kt < 16; ++kt) {
      int k0 = kt * 32 + krow * 8;
      bf16x8 hb = __builtin_bit_cast(bf16x8,
          *reinterpret_cast<const uint4*>(&h_lds[bcol * 512 + (k0 ^ sw)]));
      bf16x8 a2 = __builtin_bit_cast(bf16x8, wp4[(mt2 * 16 + kt) * 64 + lane]);
      bf16x8 a3 = __builtin_bit_cast(bf16x8, wp4[(mt3 * 16 + kt) * 64 + lane]);
      acc[0] = __builtin_amdgcn_mfma_f32_16x16x32_bf16(wreg[0][kt], hb, acc[0], 0, 0, 0);
      acc[1] = __builtin_amdgcn_mfma_f32_16x16x32_bf16(wreg[1][kt], hb, acc[1], 0, 0, 0);
      acc[2] = __builtin_amdgcn_mfma_f32_16x16x32_bf16(a2, hb, acc[2], 0, 0, 0);
      acc[3] = __builtin_amdgcn_mfma_f32_16x16x32_bf16(a3, hb, acc[3], 0, 0, 0);
    }
    // input GEMM: x[t] @ [Ws|Wr]^T  (k padded to 128; pads are zero both sides)
#pragma unroll
    for (int kx = 0; kx < 4; ++kx) {
      int k0 = kx * 32 + krow * 8;
      bf16x8 xb = __builtin_bit_cast(bf16x8,
          *reinterpret_cast<const uint4*>(&x_lds[cur][bcol * 128 + (k0 ^ sw)]));
#pragma unroll
      for (int j = 0; j < 4; ++j) {
        bf16x8 aw = __builtin_bit_cast(bf16x8,
            wp4[(FRAG_IN_OFF + (4 * wv + j) * 4 + kx) * 64 + lane]);
        acc[j] = __builtin_amdgcn_mfma_f32_16x16x32_bf16(aw, xb, acc[j], 0, 0, 0);
      }
    }
    // output GEMM for step t-1 (h_lds still holds h[t-1]); waves 0..2 only
    if (wv < 3 && t > 0) {
      f32x4 po = {0.f, 0.f, 0.f, 0.f};
#pragma unroll
      for (int kt = 0; kt < 16; ++kt) {
        int k0 = kt * 32 + krow * 8;
        bf16x8 hb = __builtin_bit_cast(bf16x8,
            *reinterpret_cast<const uint4*>(&h_lds[bcol * 512 + (k0 ^ sw)]));
        bf16x8 ao = __builtin_bit_cast(bf16x8,
            wp4[(FRAG_OUT_OFF + wv * 16 + kt) * 64 + lane]);
        po = __builtin_amdgcn_mfma_f32_16x16x32_bf16(ao, hb, po, 0, 0, 0);
      }
#pragma unroll
      for (int r = 0; r < 4; ++r) {
        int o = wv * 16 + krow * 4 + r;
        if (o < NOUT)
          out[((size_t)(t - 1) * BB + gb + bcol) * NOUT + o] = po[r] + woutb[r];
      }
    }
    __syncthreads();   // all P1 reads of h_lds/x_lds[cur] done
    // ---------------- P2 ----------------
    if (t + 1 < TT && tid < 420) {
#pragma unroll
      for (int j = 0; j < 4; ++j) {
        int e = tid * 4 + j;
        int b = e / DD, k = e - b * DD;
        x_lds[cur ^ 1][b * 128 + (k ^ ((b & 7) << 3))] = f2bf(xs[j]);
      }
    }
#pragma unroll
    for (int j = 0; j < 4; ++j) {
      int h0 = (4 * wv + j) * 16 + krow * 4;
      unsigned short hs[4];
#pragma unroll
      for (int r = 0; r < 4; ++r) {
        float v = acc[j][r] + bias_reg[j][r] + 0.05f * nrA[j][r];
        v = fmaxf(v, 0.f);
        float hn = 0.2f * v + 0.8f * hreg[j][r];
        hreg[j][r] = hn;
        hs[r] = f2bf(hn);
      }
      *reinterpret_cast<ushort4*>(&h_lds[bcol * 512 + (h0 ^ sw)]) =
          make_ushort4(hs[0], hs[1], hs[2], hs[3]);
    }
#pragma unroll
    for (int j = 0; j < 4; ++j) nrA[j] = nrB[j];
    __syncthreads();   // h[t] complete + x[t+1] staged before next P1
  }

  // final output GEMM for t = TT-1 (h_lds holds h[TT-1])
  if (wv < 3) {
    f32x4 po = {0.f, 0.f, 0.f, 0.f};
#pragma unroll
    for (int kt = 0; kt < 16; ++kt) {
      int k0 = kt * 32 + krow * 8;
      bf16x8 hb = __builtin_bit_cast(bf16x8,
          *reinterpret_cast<const uint4*>(&h_lds[bcol * 512 + (k0 ^ sw)]));
      bf16x8 ao = __builtin_bit_cast(bf16x8,
          wp4[(FRAG_OUT_OFF + wv * 16 + kt) * 64 + lane]);
      po = __builtin_amdgcn_mfma_f32_16x16x32_bf16(ao, hb, po, 0, 0, 0);
    }
#pragma unroll
    for (int r = 0; r < 4; ++r) {
      int o = wv * 16 + krow * 4 + r;
      if (o < NOUT)
        out[((size_t)(TT - 1) * BB + gb + bcol) * NOUT + o] = po[r] + woutb[r];
    }
  }
}

extern "C" void kernel_launch(void* const* d_in, const int* in_sizes, int n_in,
                              void* d_out, int out_size, void* d_ws, size_t ws_size,
                              hipStream_t stream) {
  (void)in_sizes; (void)n_in; (void)out_size; (void)ws_size;
  const float* x      = (const float*)d_in[0];
  const float* noise  = (const float*)d_in[1];
  const float* Ws_w   = (const float*)d_in[2];
  const float* Ws_b   = (const float*)d_in[3];
  const float* Wr_w   = (const float*)d_in[4];
  const float* Wrec_w = (const float*)d_in[5];
  const float* Wrec_b = (const float*)d_in[6];
  const float* mask   = (const float*)d_in[7];
  const float* Wout_w = (const float*)d_in[8];
  const float* Wout_b = (const float*)d_in[9];
  unsigned short* wp  = (unsigned short*)d_ws;   // needs 688 KB
  float* out          = (float*)d_out;

  pack_weights<<<(NFRAG_TOT * 64 + 255) / 256, 256, 0, stream>>>(
      Ws_w, Wr_w, Wrec_w, mask, Wout_w, wp);
  rnn_fused<<<16, 512, 0, stream>>>(x, noise, Ws_b, Wrec_b, Wout_b, wp, out);
}

// Round 2
// 8279.648 us; speedup vs baseline: 1.2540x; 1.2540x over previous
//
#include <hip/hip_runtime.h>

#define TT 512
#define BB 256
#define HH 512
#define DD 105
#define RS 85
#define NRULE 20
#define NOUT 33

#define NFRAG_REC 512              // 32 mtiles x 16 ktiles
#define NFRAG_IN  128              // 32 mtiles x 4 ktiles (k padded 105->128)
#define NFRAG_OUT 48               // 3 mtiles (o padded 33->48) x 16 ktiles
#define FRAG_IN_OFF  (NFRAG_REC)
#define FRAG_OUT_OFF (NFRAG_REC + NFRAG_IN)
#define NFRAG_TOT (NFRAG_REC + NFRAG_IN + NFRAG_OUT)

typedef __bf16 bf16x8 __attribute__((ext_vector_type(8)));
typedef float  f32x4  __attribute__((ext_vector_type(4)));

__device__ __forceinline__ unsigned short f2bf(float f) {
  unsigned u = __builtin_bit_cast(unsigned, f);
  u += 0x7FFFu + ((u >> 16) & 1u);            // RNE
  return (unsigned short)(u >> 16);
}

// Pack Wrec*mask, [Ws|Wr] (k padded to 128 with zeros), Wout (m padded to 48
// with zeros) into MFMA 16x16x32 A-fragment layout:
// frag f = mt*KT+kt, lane l holds M[mt*16 + (l&15)][kt*32 + (l>>4)*8 + j], j=0..7
__global__ void pack_weights(const float* __restrict__ Ws_w, const float* __restrict__ Wr_w,
                             const float* __restrict__ Wrec_w, const float* __restrict__ mask,
                             const float* __restrict__ Wout_w, unsigned short* __restrict__ wp)
{
  int gid = blockIdx.x * blockDim.x + threadIdx.x;
  if (gid >= NFRAG_TOT * 64) return;
  int f = gid >> 6, lane = gid & 63;
  int m16 = lane & 15, kg = lane >> 4;
  float v[8];
  if (f < NFRAG_REC) {
    int mt = f >> 4, kt = f & 15;
    int m = mt * 16 + m16, k0 = kt * 32 + kg * 8;
#pragma unroll
    for (int j = 0; j < 8; ++j) {
      int k = k0 + j;
      v[j] = Wrec_w[m * HH + k] * mask[m * HH + k];
    }
  } else if (f < FRAG_OUT_OFF) {
    int ff = f - FRAG_IN_OFF;
    int mt = ff >> 2, kt = ff & 3;
    int m = mt * 16 + m16, k0 = kt * 32 + kg * 8;
#pragma unroll
    for (int j = 0; j < 8; ++j) {
      int k = k0 + j;
      float val = 0.f;
      if (k < RS) val = Ws_w[m * RS + k];
      else if (k < DD) val = Wr_w[m * NRULE + (k - RS)];
      v[j] = val;
    }
  } else {
    int ff = f - FRAG_OUT_OFF;
    int mt = ff >> 4, kt = ff & 15;
    int m = mt * 16 + m16, k0 = kt * 32 + kg * 8;
#pragma unroll
    for (int j = 0; j < 8; ++j) {
      int k = k0 + j;
      v[j] = (m < NOUT) ? Wout_w[m * HH + k] : 0.f;
    }
  }
  unsigned o[4];
#pragma unroll
  for (int j = 0; j < 4; ++j)
    o[j] = (unsigned)f2bf(v[2 * j]) | ((unsigned)f2bf(v[2 * j + 1]) << 16);
  uint4 st = make_uint4(o[0], o[1], o[2], o[3]);
  *reinterpret_cast<uint4*>(wp + (size_t)f * 512 + lane * 8) = st;
}

// Persistent fused RNN kernel. 16 blocks (one per 16-row batch group), 512 thr.
// Orientation: A = W (m = h_out/o), B = state (n = b). C layout: col=lane&15=b,
// row=(lane>>4)*4+r. Each lane owns 16 (h,b) state elems in f32 registers.
// __launch_bounds__(512, 2): 2 waves/EU min -> 256-VGPR cap; register budget
// ~190 (wreg 64 + acc 16 + noise 32 + state/bias 36 + temps) -> no spill.
__global__ __launch_bounds__(512, 2)
void rnn_fused(const float* __restrict__ x, const float* __restrict__ noise,
               const float* __restrict__ Ws_b, const float* __restrict__ Wrec_b,
               const float* __restrict__ Wout_b, const unsigned short* __restrict__ wp,
               float* __restrict__ out)
{
  __shared__ unsigned short h_lds[16 * 512];      // [b][h] bf16, XOR-swizzled
  __shared__ unsigned short x_lds[2][16 * 128];   // [b][k] bf16, swizzled, zero-padded

  const int tid  = threadIdx.x;
  const int wv   = tid >> 6;
  const int lane = tid & 63;
  const int bcol = lane & 15;
  const int krow = lane >> 4;
  const int gb   = blockIdx.x * 16;
  const int sw   = (bcol & 7) << 3;               // short-index XOR (bits 3..5)

  const uint4* wp4 = reinterpret_cast<const uint4*>(wp);

  // zero LDS (h state = 0; x pads = 0; avoid NaN poison through MFMA)
  for (int i = tid; i < 16 * 512; i += 512) h_lds[i] = 0;
  {
    unsigned short* xz = &x_lds[0][0];
    for (int i = tid; i < 2 * 16 * 128; i += 512) xz[i] = 0;
  }

  // register-resident Wrec tile: mt = 4*wv (64 VGPR); tiles 4wv+1..3 streamed from L2
  bf16x8 wreg[16];
#pragma unroll
  for (int kt = 0; kt < 16; ++kt)
    wreg[kt] = __builtin_bit_cast(bf16x8, wp4[((4 * wv) * 16 + kt) * 64 + lane]);

  float bias_reg[4][4];
#pragma unroll
  for (int j = 0; j < 4; ++j)
#pragma unroll
    for (int r = 0; r < 4; ++r) {
      int h = (4 * wv + j) * 16 + krow * 4 + r;
      bias_reg[j][r] = Ws_b[h] + Wrec_b[h];
    }
  float woutb[4];
#pragma unroll
  for (int r = 0; r < 4; ++r) {
    int o = wv * 16 + krow * 4 + r;
    woutb[r] = (wv < 3 && o < NOUT) ? Wout_b[o] : 0.f;
  }

  float hreg[4][4] = {};      // f32 hidden state owned by this lane
  f32x4 nrA[4], nrB[4];       // prefetched noise (C-layout aligned float4s)

  __syncthreads();            // LDS zeros visible before staging

  // ---- stage t = 0 ----
  if (tid < 420) {
    f32x4 xv = reinterpret_cast<const f32x4*>(x + (size_t)gb * DD)[tid];
#pragma unroll
    for (int j = 0; j < 4; ++j) {
      int e = tid * 4 + j;
      int b = e / DD, k = e - b * DD;
      x_lds[0][b * 128 + (k ^ ((b & 7) << 3))] = f2bf(xv[j]);
    }
  }
  {
    const float* nb = noise + ((size_t)gb + bcol) * HH + krow * 4;
#pragma unroll
    for (int j = 0; j < 4; ++j)
      nrA[j] = *reinterpret_cast<const f32x4*>(nb + (4 * wv + j) * 16);
  }
  __syncthreads();

#pragma unroll 1
  for (int t = 0; t < TT; ++t) {
    const int cur = t & 1;
    // ---------------- P1 ----------------
    // prefetch t+1 tiles into registers (hidden under MFMA work)
    f32x4 xs = {0.f, 0.f, 0.f, 0.f};
    if (t + 1 < TT) {
      if (tid < 420)
        xs = reinterpret_cast<const f32x4*>(x + ((size_t)(t + 1) * BB + gb) * DD)[tid];
      const float* nb = noise + (((size_t)(t + 1)) * BB + gb + bcol) * HH + krow * 4;
#pragma unroll
      for (int j = 0; j < 4; ++j)
        nrB[j] = *reinterpret_cast<const f32x4*>(nb + (4 * wv + j) * 16);
    }

    f32x4 acc[4];
#pragma unroll
    for (int j = 0; j < 4; ++j) acc[j] = f32x4{0.f, 0.f, 0.f, 0.f};
    f32x4 po = {0.f, 0.f, 0.f, 0.f};

    // recurrent GEMM h[t-1] @ Wrec^T (tile 0 from regs, 1..3 streamed) with the
    // out-GEMM for step t-1 merged in (waves 0..2 reuse the same hb fragment).
    const int mt1 = 4 * wv + 1, mt2 = 4 * wv + 2, mt3 = 4 * wv + 3;
#pragma unroll
    for (int kt = 0; kt < 16; ++kt) {
      int k0 = kt * 32 + krow * 8;
      bf16x8 hb = __builtin_bit_cast(bf16x8,
          *reinterpret_cast<const uint4*>(&h_lds[bcol * 512 + (k0 ^ sw)]));
      bf16x8 a1 = __builtin_bit_cast(bf16x8, wp4[(mt1 * 16 + kt) * 64 + lane]);
      bf16x8 a2 = __builtin_bit_cast(bf16x8, wp4[(mt2 * 16 + kt) * 64 + lane]);
      bf16x8 a3 = __builtin_bit_cast(bf16x8, wp4[(mt3 * 16 + kt) * 64 + lane]);
      acc[0] = __builtin_amdgcn_mfma_f32_16x16x32_bf16(wreg[kt], hb, acc[0], 0, 0, 0);
      acc[1] = __builtin_amdgcn_mfma_f32_16x16x32_bf16(a1, hb, acc[1], 0, 0, 0);
      acc[2] = __builtin_amdgcn_mfma_f32_16x16x32_bf16(a2, hb, acc[2], 0, 0, 0);
      acc[3] = __builtin_amdgcn_mfma_f32_16x16x32_bf16(a3, hb, acc[3], 0, 0, 0);
      if (wv < 3) {
        bf16x8 ao = __builtin_bit_cast(bf16x8,
            wp4[(FRAG_OUT_OFF + wv * 16 + kt) * 64 + lane]);
        po = __builtin_amdgcn_mfma_f32_16x16x32_bf16(ao, hb, po, 0, 0, 0);
      }
    }
    // input GEMM: x[t] @ [Ws|Wr]^T  (k padded to 128; pads are zero both sides)
#pragma unroll
    for (int kx = 0; kx < 4; ++kx) {
      int k0 = kx * 32 + krow * 8;
      bf16x8 xb = __builtin_bit_cast(bf16x8,
          *reinterpret_cast<const uint4*>(&x_lds[cur][bcol * 128 + (k0 ^ sw)]));
#pragma unroll
      for (int j = 0; j < 4; ++j) {
        bf16x8 aw = __builtin_bit_cast(bf16x8,
            wp4[(FRAG_IN_OFF + (4 * wv + j) * 4 + kx) * 64 + lane]);
        acc[j] = __builtin_amdgcn_mfma_f32_16x16x32_bf16(aw, xb, acc[j], 0, 0, 0);
      }
    }
    // store out[t-1] (po accumulated against h[t-1] in the merged loop)
    if (wv < 3 && t > 0) {
#pragma unroll
      for (int r = 0; r < 4; ++r) {
        int o = wv * 16 + krow * 4 + r;
        if (o < NOUT)
          out[((size_t)(t - 1) * BB + gb + bcol) * NOUT + o] = po[r] + woutb[r];
      }
    }
    __syncthreads();   // all P1 reads of h_lds/x_lds[cur] done
    // ---------------- P2 ----------------
    if (t + 1 < TT && tid < 420) {
#pragma unroll
      for (int j = 0; j < 4; ++j) {
        int e = tid * 4 + j;
        int b = e / DD, k = e - b * DD;
        x_lds[cur ^ 1][b * 128 + (k ^ ((b & 7) << 3))] = f2bf(xs[j]);
      }
    }
#pragma unroll
    for (int j = 0; j < 4; ++j) {
      int h0 = (4 * wv + j) * 16 + krow * 4;
      unsigned short hs[4];
#pragma unroll
      for (int r = 0; r < 4; ++r) {
        float v = acc[j][r] + bias_reg[j][r] + 0.05f * nrA[j][r];
        v = fmaxf(v, 0.f);
        float hn = 0.2f * v + 0.8f * hreg[j][r];
        hreg[j][r] = hn;
        hs[r] = f2bf(hn);
      }
      *reinterpret_cast<ushort4*>(&h_lds[bcol * 512 + (h0 ^ sw)]) =
          make_ushort4(hs[0], hs[1], hs[2], hs[3]);
    }
#pragma unroll
    for (int j = 0; j < 4; ++j) nrA[j] = nrB[j];
    __syncthreads();   // h[t] complete + x[t+1] staged before next P1
  }

  // final output GEMM for t = TT-1 (h_lds holds h[TT-1])
  if (wv < 3) {
    f32x4 po = {0.f, 0.f, 0.f, 0.f};
#pragma unroll
    for (int kt = 0; kt < 16; ++kt) {
      int k0 = kt * 32 + krow * 8;
      bf16x8 hb = __builtin_bit_cast(bf16x8,
          *reinterpret_cast<const uint4*>(&h_lds[bcol * 512 + (k0 ^ sw)]));
      bf16x8 ao = __builtin_bit_cast(bf16x8,
          wp4[(FRAG_OUT_OFF + wv * 16 + kt) * 64 + lane]);
      po = __builtin_amdgcn_mfma_f32_16x16x32_bf16(ao, hb, po, 0, 0, 0);
    }
#pragma unroll
    for (int r = 0; r < 4; ++r) {
      int o = wv * 16 + krow * 4 + r;
      if (o < NOUT)
        out[((size_t)(TT - 1) * BB + gb + bcol) * NOUT + o] = po[r] + woutb[r];
    }
  }
}

extern "C" void kernel_launch(void* const* d_in, const int* in_sizes, int n_in,
                              void* d_out, int out_size, void* d_ws, size_t ws_size,
                              hipStream_t stream) {
  (void)in_sizes; (void)n_in; (void)out_size; (void)ws_size;
  const float* x      = (const float*)d_in[0];
  const float* noise  = (const float*)d_in[1];
  const float* Ws_w   = (const float*)d_in[2];
  const float* Ws_b   = (const float*)d_in[3];
  const float* Wr_w   = (const float*)d_in[4];
  const float* Wrec_w = (const float*)d_in[5];
  const float* Wrec_b = (const float*)d_in[6];
  const float* mask   = (const float*)d_in[7];
  const float* Wout_w = (const float*)d_in[8];
  const float* Wout_b = (const float*)d_in[9];
  unsigned short* wp  = (unsigned short*)d_ws;   // needs 688 KB
  float* out          = (float*)d_out;

  pack_weights<<<(NFRAG_TOT * 64 + 255) / 256, 256, 0, stream>>>(
      Ws_w, Wr_w, Wrec_w, mask, Wout_w, wp);
  rnn_fused<<<16, 512, 0, stream>>>(x, noise, Ws_b, Wrec_b, Wout_b, wp, out);
}

// Round 3
// 3566.243 us; speedup vs baseline: 2.9114x; 2.3217x over previous
//
#include <hip/hip_runtime.h>

#define TT 512
#define BB 256
#define HH 512
#define DD 105
#define RS 85
#define NRULE 20
#define NOUT 33
#define HALF 256

#define NFRAG_REC 512              // 32 mtiles x 16 ktiles
#define NFRAG_IN  128              // 32 mtiles x 4 ktiles (k padded 105->128)
#define NFRAG_OUT 48               // 3 mtiles (o padded 33->48) x 16 ktiles
#define FRAG_IN_OFF  (NFRAG_REC)
#define FRAG_OUT_OFF (NFRAG_REC + NFRAG_IN)
#define NFRAG_TOT (NFRAG_REC + NFRAG_IN + NFRAG_OUT)

#define WP_BYTES   ((size_t)NFRAG_TOT * 1024)          // 704512
#define HX_OFF     WP_BYTES
#define HX_BYTES   ((size_t)32 * 16 * HALF * 2)        // 262144
#define FLAGS_OFF  (HX_OFF + HX_BYTES)                 // 966656

typedef __bf16 bf16x8 __attribute__((ext_vector_type(8)));
typedef float  f32x4  __attribute__((ext_vector_type(4)));

__device__ __forceinline__ unsigned short f2bf(float f) {
  unsigned u = __builtin_bit_cast(unsigned, f);
  u += 0x7FFFu + ((u >> 16) & 1u);            // RNE
  return (unsigned short)(u >> 16);
}

// Pack Wrec*mask, [Ws|Wr] (k padded to 128), Wout (m padded to 48) into MFMA
// 16x16x32 A-frag layout: frag f, lane l holds M[mt*16+(l&15)][kt*32+(l>>4)*8+j]
__global__ void pack_weights(const float* __restrict__ Ws_w, const float* __restrict__ Wr_w,
                             const float* __restrict__ Wrec_w, const float* __restrict__ mask,
                             const float* __restrict__ Wout_w, unsigned short* __restrict__ wp)
{
  int gid = blockIdx.x * blockDim.x + threadIdx.x;
  if (gid >= NFRAG_TOT * 64) return;
  int f = gid >> 6, lane = gid & 63;
  int m16 = lane & 15, kg = lane >> 4;
  float v[8];
  if (f < NFRAG_REC) {
    int mt = f >> 4, kt = f & 15;
    int m = mt * 16 + m16, k0 = kt * 32 + kg * 8;
#pragma unroll
    for (int j = 0; j < 8; ++j) {
      int k = k0 + j;
      v[j] = Wrec_w[m * HH + k] * mask[m * HH + k];
    }
  } else if (f < FRAG_OUT_OFF) {
    int ff = f - FRAG_IN_OFF;
    int mt = ff >> 2, kt = ff & 3;
    int m = mt * 16 + m16, k0 = kt * 32 + kg * 8;
#pragma unroll
    for (int j = 0; j < 8; ++j) {
      int k = k0 + j;
      float val = 0.f;
      if (k < RS) val = Ws_w[m * RS + k];
      else if (k < DD) val = Wr_w[m * NRULE + (k - RS)];
      v[j] = val;
    }
  } else {
    int ff = f - FRAG_OUT_OFF;
    int mt = ff >> 4, kt = ff & 15;
    int m = mt * 16 + m16, k0 = kt * 32 + kg * 8;
#pragma unroll
    for (int j = 0; j < 8; ++j) {
      int k = k0 + j;
      v[j] = (m < NOUT) ? Wout_w[m * HH + k] : 0.f;
    }
  }
  unsigned o[4];
#pragma unroll
  for (int j = 0; j < 4; ++j)
    o[j] = (unsigned)f2bf(v[2 * j]) | ((unsigned)f2bf(v[2 * j + 1]) << 16);
  uint4 st = make_uint4(o[0], o[1], o[2], o[3]);
  *reinterpret_cast<uint4*>(wp + (size_t)f * 512 + lane * 8) = st;
}

// 32 blocks: group g = bid&15 (16 batch rows), half hf = bid>>4 (256 h-rows).
// All weights resident: Wrec slice in AGPRs (2 mtiles/wave), Win slice in LDS.
// Per-step pair exchange of h halves via agent-scope (L2-bypass) atomics.
__global__ __launch_bounds__(512, 2)
void rnn_fused(const float* __restrict__ x, const float* __restrict__ noise,
               const float* __restrict__ Ws_b, const float* __restrict__ Wrec_b,
               const float* __restrict__ Wout_b, unsigned char* __restrict__ ws,
               float* __restrict__ out)
{
  __shared__ unsigned short h_lds[16 * 512];        // [b][h] bf16, XOR-swizzled (16 KB)
  __shared__ unsigned short x_lds[2][16 * 128];     // [b][k] bf16, swizzled (8 KB)
  __shared__ unsigned short win_lds[64 * 512];      // 64 input-W frags (64 KB)

  const int tid  = threadIdx.x;
  const int wv   = tid >> 6;
  const int lane = tid & 63;
  const int bcol = lane & 15;
  const int krow = lane >> 4;
  const int bid  = blockIdx.x;
  const int g    = bid & 15;
  const int hf   = bid >> 4;                         // 0 or 1
  const int gb   = g * 16;
  const int hbase = hf * HALF;
  const int sw   = (bcol & 7) << 3;
  const bool outduty = (hf == 0);

  const unsigned short* wp = (const unsigned short*)ws;
  const uint4* wp4 = reinterpret_cast<const uint4*>(wp);
  unsigned long long* hx_own =
      (unsigned long long*)(ws + HX_OFF + (size_t)bid * 8192);
  unsigned long long* hx_par =
      (unsigned long long*)(ws + HX_OFF + (size_t)(bid ^ 16) * 8192);
  int* flags = (int*)(ws + FLAGS_OFF);
  const int phbase = (hf ^ 1) * HALF;

  // zero LDS state
  for (int i = tid; i < 16 * 512; i += 512) h_lds[i] = 0;
  {
    unsigned short* xz = &x_lds[0][0];
    for (int i = tid; i < 2 * 16 * 128; i += 512) xz[i] = 0;
  }
  // stage Win slice (this half's 16 mtiles x 4 kx = 64 frags) into LDS
  for (int c = tid; c < 64 * 64; c += 512) {
    int fl = c >> 6, l = c & 63;
    int mtg = hf * 16 + (fl >> 2), kx = fl & 3;
    uint4 w = wp4[(FRAG_IN_OFF + mtg * 4 + kx) * 64 + l];
    *reinterpret_cast<uint4*>(&win_lds[fl * 512 + l * 8]) = w;
  }

  // Wrec slice: 2 mtiles per wave, MFMA-A-only -> AGPR-resident (128 regs)
  bf16x8 wreg[2][16];
#pragma unroll
  for (int j = 0; j < 2; ++j)
#pragma unroll
    for (int kt = 0; kt < 16; ++kt)
      wreg[j][kt] = __builtin_bit_cast(bf16x8,
          wp4[((hf * 16 + 2 * wv + j) * 16 + kt) * 64 + lane]);

  float bias_reg[2][4];
#pragma unroll
  for (int j = 0; j < 2; ++j)
#pragma unroll
    for (int r = 0; r < 4; ++r) {
      int h = hbase + (2 * wv + j) * 16 + krow * 4 + r;
      bias_reg[j][r] = Ws_b[h] + Wrec_b[h];
    }
  float woutb[4];
#pragma unroll
  for (int r = 0; r < 4; ++r) {
    int o = wv * 16 + krow * 4 + r;
    woutb[r] = (outduty && wv < 3 && o < NOUT) ? Wout_b[o] : 0.f;
  }

  float hreg[2][4] = {};
  f32x4 nrA[2], nrB[2];

  __syncthreads();

  // stage t = 0
  if (tid < 420) {
    f32x4 xv = reinterpret_cast<const f32x4*>(x + (size_t)gb * DD)[tid];
#pragma unroll
    for (int j = 0; j < 4; ++j) {
      int e = tid * 4 + j;
      int b = e / DD, k = e - b * DD;
      x_lds[0][b * 128 + (k ^ ((b & 7) << 3))] = f2bf(xv[j]);
    }
  }
  {
    const float* nb = noise + ((size_t)gb + bcol) * HH + hbase + krow * 4;
#pragma unroll
    for (int j = 0; j < 2; ++j)
      nrA[j] = *reinterpret_cast<const f32x4*>(nb + (2 * wv + j) * 16);
  }
  __syncthreads();

#pragma unroll 1
  for (int t = 0; t < TT; ++t) {
    const int cur = t & 1;
    // ---------------- P1: GEMMs against h[t-1], x[t] ----------------
    f32x4 xs = {0.f, 0.f, 0.f, 0.f};
    if (t + 1 < TT) {
      if (tid < 420)
        xs = reinterpret_cast<const f32x4*>(x + ((size_t)(t + 1) * BB + gb) * DD)[tid];
      const float* nb = noise + (((size_t)(t + 1)) * BB + gb + bcol) * HH + hbase + krow * 4;
#pragma unroll
      for (int j = 0; j < 2; ++j)
        nrB[j] = *reinterpret_cast<const f32x4*>(nb + (2 * wv + j) * 16);
    }

    f32x4 acc[2];
    acc[0] = f32x4{0.f, 0.f, 0.f, 0.f};
    acc[1] = f32x4{0.f, 0.f, 0.f, 0.f};
    f32x4 po = {0.f, 0.f, 0.f, 0.f};

#pragma unroll
    for (int kt = 0; kt < 16; ++kt) {
      int k0 = kt * 32 + krow * 8;
      bf16x8 hb = __builtin_bit_cast(bf16x8,
          *reinterpret_cast<const uint4*>(&h_lds[bcol * 512 + (k0 ^ sw)]));
      acc[0] = __builtin_amdgcn_mfma_f32_16x16x32_bf16(wreg[0][kt], hb, acc[0], 0, 0, 0);
      acc[1] = __builtin_amdgcn_mfma_f32_16x16x32_bf16(wreg[1][kt], hb, acc[1], 0, 0, 0);
      if (outduty && wv < 3) {
        bf16x8 ao = __builtin_bit_cast(bf16x8,
            wp4[(FRAG_OUT_OFF + wv * 16 + kt) * 64 + lane]);
        po = __builtin_amdgcn_mfma_f32_16x16x32_bf16(ao, hb, po, 0, 0, 0);
      }
    }
#pragma unroll
    for (int kx = 0; kx < 4; ++kx) {
      int k0 = kx * 32 + krow * 8;
      bf16x8 xb = __builtin_bit_cast(bf16x8,
          *reinterpret_cast<const uint4*>(&x_lds[cur][bcol * 128 + (k0 ^ sw)]));
#pragma unroll
      for (int j = 0; j < 2; ++j) {
        bf16x8 aw = __builtin_bit_cast(bf16x8,
            *reinterpret_cast<const uint4*>(&win_lds[((2 * wv + j) * 4 + kx) * 512 + lane * 8]));
        acc[j] = __builtin_amdgcn_mfma_f32_16x16x32_bf16(aw, xb, acc[j], 0, 0, 0);
      }
    }
    if (outduty && wv < 3 && t > 0) {
#pragma unroll
      for (int r = 0; r < 4; ++r) {
        int o = wv * 16 + krow * 4 + r;
        if (o < NOUT)
          out[((size_t)(t - 1) * BB + gb + bcol) * NOUT + o] = po[r] + woutb[r];
      }
    }
    __syncthreads();   // all P1 reads of h_lds / x_lds[cur] done
    // ---------------- P2: state update + own-half publish ----------------
#pragma unroll
    for (int j = 0; j < 2; ++j) {
      unsigned short hs[4];
#pragma unroll
      for (int r = 0; r < 4; ++r) {
        float v = acc[j][r] + bias_reg[j][r] + 0.05f * nrA[j][r];
        v = fmaxf(v, 0.f);
        float hn = 0.2f * v + 0.8f * hreg[j][r];
        hreg[j][r] = hn;
        hs[r] = f2bf(hn);
      }
      unsigned long long pk = (unsigned long long)hs[0]
                            | ((unsigned long long)hs[1] << 16)
                            | ((unsigned long long)hs[2] << 32)
                            | ((unsigned long long)hs[3] << 48);
      // publish to partner via L2-bypassing agent-scope store
      __hip_atomic_store(&hx_own[(bcol * HALF + (2 * wv + j) * 16 + krow * 4) >> 2],
                         pk, __ATOMIC_RELAXED, __HIP_MEMORY_SCOPE_AGENT);
      int hg = hbase + (2 * wv + j) * 16 + krow * 4;
      *reinterpret_cast<ushort4*>(&h_lds[bcol * 512 + (hg ^ sw)]) =
          make_ushort4(hs[0], hs[1], hs[2], hs[3]);
    }
    if (t + 1 < TT && tid < 420) {
#pragma unroll
      for (int j = 0; j < 4; ++j) {
        int e = tid * 4 + j;
        int b = e / DD, k = e - b * DD;
        x_lds[cur ^ 1][b * 128 + (k ^ ((b & 7) << 3))] = f2bf(xs[j]);
      }
    }
#pragma unroll
    for (int j = 0; j < 2; ++j) nrA[j] = nrB[j];
    __syncthreads();   // all waves' hx stores drained (vmcnt(0) at barrier)
    // ---------------- handshake ----------------
    if (tid == 0) {
      __hip_atomic_store(&flags[bid], t + 1, __ATOMIC_RELEASE, __HIP_MEMORY_SCOPE_AGENT);
      while (__hip_atomic_load(&flags[bid ^ 16], __ATOMIC_ACQUIRE,
                               __HIP_MEMORY_SCOPE_AGENT) <= t) {
        __builtin_amdgcn_s_sleep(2);
      }
    }
    __syncthreads();   // partner half is globally visible
    // merge partner half into h_lds (L2-bypassing loads)
    {
      unsigned long long v0 = __hip_atomic_load(&hx_par[tid * 2],
                                  __ATOMIC_RELAXED, __HIP_MEMORY_SCOPE_AGENT);
      unsigned long long v1 = __hip_atomic_load(&hx_par[tid * 2 + 1],
                                  __ATOMIC_RELAXED, __HIP_MEMORY_SCOPE_AGENT);
      int e0 = tid * 8;
      int b = e0 >> 8, hloc = e0 & 255;
      int hg = phbase + hloc;                        // hloc % 8 == 0 -> contiguous
      unsigned long long* dst =
          (unsigned long long*)&h_lds[b * 512 + (hg ^ ((b & 7) << 3))];
      dst[0] = v0; dst[1] = v1;
    }
    __syncthreads();   // h[t] complete for next P1
  }

  // final out for t = TT-1
  if (outduty && wv < 3) {
    f32x4 po = {0.f, 0.f, 0.f, 0.f};
#pragma unroll
    for (int kt = 0; kt < 16; ++kt) {
      int k0 = kt * 32 + krow * 8;
      bf16x8 hb = __builtin_bit_cast(bf16x8,
          *reinterpret_cast<const uint4*>(&h_lds[bcol * 512 + (k0 ^ sw)]));
      bf16x8 ao = __builtin_bit_cast(bf16x8,
          wp4[(FRAG_OUT_OFF + wv * 16 + kt) * 64 + lane]);
      po = __builtin_amdgcn_mfma_f32_16x16x32_bf16(ao, hb, po, 0, 0, 0);
    }
#pragma unroll
    for (int r = 0; r < 4; ++r) {
      int o = wv * 16 + krow * 4 + r;
      if (o < NOUT)
        out[((size_t)(TT - 1) * BB + gb + bcol) * NOUT + o] = po[r] + woutb[r];
    }
  }
}

extern "C" void kernel_launch(void* const* d_in, const int* in_sizes, int n_in,
                              void* d_out, int out_size, void* d_ws, size_t ws_size,
                              hipStream_t stream) {
  (void)in_sizes; (void)n_in; (void)out_size; (void)ws_size;
  const float* x      = (const float*)d_in[0];
  const float* noise  = (const float*)d_in[1];
  const float* Ws_w   = (const float*)d_in[2];
  const float* Ws_b   = (const float*)d_in[3];
  const float* Wr_w   = (const float*)d_in[4];
  const float* Wrec_w = (const float*)d_in[5];
  const float* Wrec_b = (const float*)d_in[6];
  const float* mask   = (const float*)d_in[7];
  const float* Wout_w = (const float*)d_in[8];
  const float* Wout_b = (const float*)d_in[9];
  unsigned char* ws   = (unsigned char*)d_ws;        // needs ~945 KB
  float* out          = (float*)d_out;

  // reset handshake flags each launch (graph-replay safe)
  hipMemsetAsync(ws + FLAGS_OFF, 0, 32 * sizeof(int), stream);
  pack_weights<<<(NFRAG_TOT * 64 + 255) / 256, 256, 0, stream>>>(
      Ws_w, Wr_w, Wrec_w, mask, Wout_w, (unsigned short*)ws);
  rnn_fused<<<32, 512, 0, stream>>>(x, noise, Ws_b, Wrec_b, Wout_b, ws, out);
}